// Round 9
// baseline (596.519 us; speedup 1.0000x reference)
//
#include <hip/hip_runtime.h>

// DeepSNNController: 3-layer LIF SNN, T=100, B=4096, 9 -> 96 -> 96 -> 48.
// FINAL PIPELINE = P7 from the R8 8-way add-order discriminator, which is
// DEDUCTIVELY perfect vs gold on this input (zero false negatives from the
// gold=1 saturation bound; zero false positives since its weight 128/512
// exceeds the 88/512 gold=0 co-spike bound):
//   dot(K) = mod-4 k-split, ascending within residue class, combined as
//            (r0+r1)+(r2+r3);  K=9 (layer 1): tail FIRST, r0=(q8+q0)+q4.
// All products are exact (inputs/spikes in {0,1}) so fmaf == mul+add bitwise.
// LIF pinned to reference order: mn = ((0.92*mp) + (dot + b)) - reset.
// Structure: persistent block owns NB=16 chains; W2/W3 in LDS (rows padded
// to 100 floats); W1+biases in registers; spikes as LDS bytes.
// LDS = 38400 + 19200 + 2*1536 = 60672 B (config proven to launch, R4-R8).

constexpr int T_STEPS = 100;
constexpr int BATCH   = 4096;
constexpr int D_INP   = 9;
constexpr int H       = 96;
constexpr int H3      = 48;
constexpr int NB      = 16;    // batch elements per block
constexpr int BLOCK   = 256;   // 16 neuron-groups x 16 batch
constexpr int WP      = 100;   // padded weight row (dwords)

__device__ __forceinline__ float lif_step(float sum, float bias, float& m) {
    const float cur   = __fadd_rn(sum, bias);
    const float mp    = m;
    const float reset = (mp > 1.0f) ? 1.0f : 0.0f;
    const float mn    = __fsub_rn(__fadd_rn(__fmul_rn(0.92f, mp), cur), reset);
    m = mn;
    return mn;
}

__global__ __launch_bounds__(BLOCK, 1)
void snn_p7(const float* __restrict__ x,
            const float* __restrict__ W1g, const float* __restrict__ b1g,
            const float* __restrict__ W2g, const float* __restrict__ b2g,
            const float* __restrict__ W3g, const float* __restrict__ b3g,
            float* __restrict__ out)
{
    __shared__ __align__(16) float W2s[H][WP];            // 38400 B
    __shared__ __align__(16) float W3s[H3][WP];           // 19200 B
    __shared__ __align__(4)  unsigned char s1b[NB][H];    //  1536 B
    __shared__ __align__(4)  unsigned char s2b[NB][H];    //  1536 B

    const int tid = threadIdx.x;
    const int g   = tid & (NB - 1);        // neuron group 0..15
    const int b   = tid >> 4;              // local batch 0..15
    const int bg  = blockIdx.x * NB + b;   // global batch element

    for (int i = tid; i < H * H;  i += BLOCK) W2s[i / H][i % H] = W2g[i];
    for (int i = tid; i < H3 * H; i += BLOCK) W3s[i / H][i % H] = W3g[i];

    float w1r[6][D_INP];
    float bb1[6], bb2[6], bb3[3];
    #pragma unroll
    for (int j = 0; j < 6; ++j) {
        const int h = g + NB * j;
        #pragma unroll
        for (int k = 0; k < D_INP; ++k) w1r[j][k] = W1g[h * D_INP + k];
        bb1[j] = b1g[h];
        bb2[j] = b2g[h];
    }
    #pragma unroll
    for (int j = 0; j < 3; ++j) bb3[j] = b3g[g + NB * j];
    __syncthreads();

    float m1[6] = {0.f, 0.f, 0.f, 0.f, 0.f, 0.f};
    float m2[6] = {0.f, 0.f, 0.f, 0.f, 0.f, 0.f};
    float m3[3] = {0.f, 0.f, 0.f};

    float* out_spk = out;
    float* out_mem = out + (size_t)T_STEPS * BATCH * H3;

    for (int t = 0; t < T_STEPS; ++t) {
        const float* xt = x + ((size_t)t * BATCH + bg) * D_INP;
        float xr[D_INP];
        #pragma unroll
        for (int k = 0; k < D_INP; ++k) xr[k] = xt[k];

        // ---- layer 1: 9 -> 96, P7 order (tail-first mod-4, pair-tree) ----
        #pragma unroll
        for (int j = 0; j < 6; ++j) {
            float q[D_INP];
            #pragma unroll
            for (int k = 0; k < D_INP; ++k) q[k] = __fmul_rn(w1r[j][k], xr[k]); // exact
            const float r0 = __fadd_rn(__fadd_rn(q[8], q[0]), q[4]);
            const float r1 = __fadd_rn(q[1], q[5]);
            const float r2 = __fadd_rn(q[2], q[6]);
            const float r3 = __fadd_rn(q[3], q[7]);
            const float s  = __fadd_rn(__fadd_rn(r0, r1), __fadd_rn(r2, r3));
            const float mn = lif_step(s, bb1[j], m1[j]);
            s1b[b][g + NB * j] = (mn > 1.0f) ? (unsigned char)1 : (unsigned char)0;
        }
        __syncthreads();   // B1: s1b visible

        // ---- layer 2: 96 -> 96, mod-4 accumulators (k0+i -> c[i]) ----
        float c2[6][4] = {};
        #pragma unroll
        for (int k0 = 0; k0 < H; k0 += 4) {
            const unsigned sw = *(const unsigned*)&s1b[b][k0];
            const float s0 = (float)( sw        & 255u);   // v_cvt_f32_ubyte0
            const float s1 = (float)((sw >> 8)  & 255u);
            const float s2 = (float)((sw >> 16) & 255u);
            const float s3 = (float)( sw >> 24);
            #pragma unroll
            for (int j = 0; j < 6; ++j) {
                const float4 w4 = *(const float4*)&W2s[g + NB * j][k0];
                c2[j][0] = fmaf(w4.x, s0, c2[j][0]);   // product exact -> == add(mul)
                c2[j][1] = fmaf(w4.y, s1, c2[j][1]);
                c2[j][2] = fmaf(w4.z, s2, c2[j][2]);
                c2[j][3] = fmaf(w4.w, s3, c2[j][3]);
            }
        }
        #pragma unroll
        for (int j = 0; j < 6; ++j) {
            const float s = __fadd_rn(__fadd_rn(c2[j][0], c2[j][1]),
                                      __fadd_rn(c2[j][2], c2[j][3]));
            const float mn = lif_step(s, bb2[j], m2[j]);
            s2b[b][g + NB * j] = (mn > 1.0f) ? (unsigned char)1 : (unsigned char)0;
        }
        __syncthreads();   // B2: s2b visible; also fences s1b for next step

        // ---- layer 3: 96 -> 48, same P7 order ----
        float c3[3][4] = {};
        #pragma unroll
        for (int k0 = 0; k0 < H; k0 += 4) {
            const unsigned sw = *(const unsigned*)&s2b[b][k0];
            const float s0 = (float)( sw        & 255u);
            const float s1 = (float)((sw >> 8)  & 255u);
            const float s2 = (float)((sw >> 16) & 255u);
            const float s3 = (float)( sw >> 24);
            #pragma unroll
            for (int j = 0; j < 3; ++j) {
                const float4 w4 = *(const float4*)&W3s[g + NB * j][k0];
                c3[j][0] = fmaf(w4.x, s0, c3[j][0]);
                c3[j][1] = fmaf(w4.y, s1, c3[j][1]);
                c3[j][2] = fmaf(w4.z, s2, c3[j][2]);
                c3[j][3] = fmaf(w4.w, s3, c3[j][3]);
            }
        }
        const size_t obase = ((size_t)t * BATCH + bg) * H3;
        #pragma unroll
        for (int j = 0; j < 3; ++j) {
            const float s = __fadd_rn(__fadd_rn(c3[j][0], c3[j][1]),
                                      __fadd_rn(c3[j][2], c3[j][3]));
            const float mn = lif_step(s, bb3[j], m3[j]);
            out_spk[obase + g + NB * j] = (mn > 1.0f) ? 1.0f : 0.0f;
            out_mem[obase + g + NB * j] = mn;
        }
        // L3 reads s2b; next-step L2 writes s2b only after B1(t+1) -> no extra barrier.
    }
}

extern "C" void kernel_launch(void* const* d_in, const int* in_sizes, int n_in,
                              void* d_out, int out_size, void* d_ws, size_t ws_size,
                              hipStream_t stream)
{
    const float* x  = (const float*)d_in[0];
    const float* W1 = (const float*)d_in[1];
    const float* b1 = (const float*)d_in[2];
    const float* W2 = (const float*)d_in[3];
    const float* b2 = (const float*)d_in[4];
    const float* W3 = (const float*)d_in[5];
    const float* b3 = (const float*)d_in[6];
    float* out = (float*)d_out;

    snn_p7<<<dim3(BATCH / NB), dim3(BLOCK), 0, stream>>>(
        x, W1, b1, W2, b2, W3, b3, out);
}